// Round 1
// baseline (2873.642 us; speedup 1.0000x reference)
//
#include <hip/hip_runtime.h>

#define N_NODES_C 50000
#define N_EDGES_C 800000
#define IN_FEATS_C 128
#define HEADS_C 8
#define HD_C 256            // HEADS * OUT_FEATS
#define NEG_SLOPE_C 0.2f

// ---------------- GEMM: feat_hd[n][c] = sum_k feat[n][k] * W[c][k] ----------------
// Tile: 64 nodes x 128 channels, K=128 staged in two halves of 64.
// LDS: sW [k][c] stride 132, sF [k][n] stride 68  -> 51200 B total.
#define TILE_N 64
#define TILE_C 128
#define KSPLIT 64
#define SW_STRIDE 132
#define SF_STRIDE 68

__global__ __launch_bounds__(256) void gemm_kernel(
    const float* __restrict__ feat, const float* __restrict__ W,
    float* __restrict__ feat_hd) {
  __shared__ float sW[KSPLIT * SW_STRIDE];
  __shared__ float sF[KSPLIT * SF_STRIDE];
  const int bid = blockIdx.x;
  const int ct = bid & 1;        // channel tile: 0 or 1 (128 channels each)
  const int nt = bid >> 1;       // node tile
  const int n0 = nt * TILE_N;
  const int c0 = ct * TILE_C;
  const int t = threadIdx.x;
  const int tc = t & 15;         // 16 channel groups * 8 ch
  const int tn = t >> 4;         // 16 node groups * 4 nodes

  float acc[4][8];
#pragma unroll
  for (int i = 0; i < 4; ++i)
#pragma unroll
    for (int j = 0; j < 8; ++j) acc[i][j] = 0.f;

  for (int ks = 0; ks < IN_FEATS_C; ks += KSPLIT) {
    __syncthreads();
    // stage W half: 128 c x 64 k
#pragma unroll
    for (int i = 0; i < (TILE_C * KSPLIT) / 256; ++i) {
      int idx = t + i * 256;
      int c = idx >> 6;          // 0..127
      int k = idx & 63;          // 0..63
      sW[k * SW_STRIDE + c] = W[(c0 + c) * IN_FEATS_C + ks + k];
    }
    // stage feat half: 64 n x 64 k (zero-pad past N)
#pragma unroll
    for (int i = 0; i < (TILE_N * KSPLIT) / 256; ++i) {
      int idx = t + i * 256;
      int n = idx >> 6;          // 0..63
      int k = idx & 63;
      int gn = n0 + n;
      sF[k * SF_STRIDE + n] = (gn < N_NODES_C) ? feat[gn * IN_FEATS_C + ks + k] : 0.f;
    }
    __syncthreads();

    const float* pW = sW + tc * 8;
    const float* pF = sF + tn * 4;
#pragma unroll 4
    for (int k = 0; k < KSPLIT; ++k) {
      float4 w0 = *(const float4*)(pW + k * SW_STRIDE);
      float4 w1 = *(const float4*)(pW + k * SW_STRIDE + 4);
      float4 f0 = *(const float4*)(pF + k * SF_STRIDE);
      float wv[8] = {w0.x, w0.y, w0.z, w0.w, w1.x, w1.y, w1.z, w1.w};
      float fv[4] = {f0.x, f0.y, f0.z, f0.w};
#pragma unroll
      for (int n = 0; n < 4; ++n)
#pragma unroll
        for (int c = 0; c < 8; ++c) acc[n][c] = fmaf(fv[n], wv[c], acc[n][c]);
    }
  }

#pragma unroll
  for (int n = 0; n < 4; ++n) {
    int gn = n0 + tn * 4 + n;
    if (gn >= N_NODES_C) continue;
    float4 o0 = make_float4(acc[n][0], acc[n][1], acc[n][2], acc[n][3]);
    float4 o1 = make_float4(acc[n][4], acc[n][5], acc[n][6], acc[n][7]);
    float* p = feat_hd + (size_t)gn * HD_C + c0 + tc * 8;
    *(float4*)p = o0;
    *(float4*)(p + 4) = o1;
  }
}

// ---------------- el/er: per-node attention logits ----------------
// wave per node; lane owns 4 channels (all within one head: head = lane/8)
__global__ __launch_bounds__(256) void elr_kernel(
    const float* __restrict__ feat_hd, const float* __restrict__ attn_l,
    const float* __restrict__ attn_r, float* __restrict__ el,
    float* __restrict__ er) {
  int gid = blockIdx.x * 256 + threadIdx.x;
  int node = gid >> 6;
  int lane = threadIdx.x & 63;
  if (node >= N_NODES_C) return;
  float4 al = *(const float4*)&attn_l[lane * 4];
  float4 ar = *(const float4*)&attn_r[lane * 4];
  float4 f = *(const float4*)&feat_hd[(size_t)node * HD_C + lane * 4];
  float pl = f.x * al.x + f.y * al.y + f.z * al.z + f.w * al.w;
  float pr = f.x * ar.x + f.y * ar.y + f.z * ar.z + f.w * ar.w;
  pl += __shfl_xor(pl, 1); pr += __shfl_xor(pr, 1);
  pl += __shfl_xor(pl, 2); pr += __shfl_xor(pr, 2);
  pl += __shfl_xor(pl, 4); pr += __shfl_xor(pr, 4);
  if ((lane & 7) == 0) {
    el[node * HEADS_C + (lane >> 3)] = pl;
    er[node * HEADS_C + (lane >> 3)] = pr;
  }
}

// ---------------- z: softmax denominator per (dst, head) ----------------
// No segment_max needed: |e| <= ~6 so exp(e) is safely bounded; exp(e)/sum(exp(e))
// is mathematically identical to the max-subtracted form.
__global__ __launch_bounds__(256) void z_kernel(
    const float* __restrict__ el, const float* __restrict__ er,
    const int* __restrict__ src, const int* __restrict__ dst,
    float* __restrict__ z) {
  int idx = blockIdx.x * 256 + threadIdx.x;
  if (idx >= N_EDGES_C * HEADS_C) return;
  int e = idx >> 3;
  int h = idx & 7;
  int s = src[e];
  int d = dst[e];
  float x = el[s * HEADS_C + h] + er[d * HEADS_C + h];
  x = x > 0.f ? x : NEG_SLOPE_C * x;
  atomicAdd(&z[d * HEADS_C + h], __expf(x));
}

// ---------------- aggregation: out[d] += feat_hd[s] * a ----------------
// wave per edge; lane owns 4 contiguous channels (head = lane/8)
__global__ __launch_bounds__(256) void agg_kernel(
    const float* __restrict__ feat_hd, const float* __restrict__ el,
    const float* __restrict__ er, const int* __restrict__ src,
    const int* __restrict__ dst, const float* __restrict__ z,
    float* __restrict__ out) {
  int gid = blockIdx.x * 256 + threadIdx.x;
  int e = gid >> 6;
  int lane = threadIdx.x & 63;
  if (e >= N_EDGES_C) return;
  int s = src[e];
  int d = dst[e];
  int h = lane >> 3;
  float x = el[s * HEADS_C + h] + er[d * HEADS_C + h];
  x = x > 0.f ? x : NEG_SLOPE_C * x;
  float a = __expf(x) / z[d * HEADS_C + h];
  int c = lane * 4;
  float4 f = *(const float4*)&feat_hd[(size_t)s * HD_C + c];
  float* po = out + (size_t)d * HD_C + c;
  atomicAdd(po + 0, f.x * a);
  atomicAdd(po + 1, f.y * a);
  atomicAdd(po + 2, f.z * a);
  atomicAdd(po + 3, f.w * a);
}

extern "C" void kernel_launch(void* const* d_in, const int* in_sizes, int n_in,
                              void* d_out, int out_size, void* d_ws, size_t ws_size,
                              hipStream_t stream) {
  const float* feat   = (const float*)d_in[0];
  const float* W      = (const float*)d_in[1];
  const float* attn_l = (const float*)d_in[2];
  const float* attn_r = (const float*)d_in[3];
  const int* src      = (const int*)d_in[4];
  const int* dst      = (const int*)d_in[5];
  float* out = (float*)d_out;

  float* ws = (float*)d_ws;
  float* feat_hd = ws;                                   // 50000*256 = 12.8M floats
  float* el = feat_hd + (size_t)N_NODES_C * HD_C;        // 400K
  float* er = el + (size_t)N_NODES_C * HEADS_C;          // 400K
  float* z  = er + (size_t)N_NODES_C * HEADS_C;          // 400K

  hipMemsetAsync(out, 0, (size_t)N_NODES_C * HD_C * sizeof(float), stream);
  hipMemsetAsync(z, 0, (size_t)N_NODES_C * HEADS_C * sizeof(float), stream);

  int node_tiles = (N_NODES_C + TILE_N - 1) / TILE_N;    // 782
  gemm_kernel<<<node_tiles * 2, 256, 0, stream>>>(feat, W, feat_hd);

  elr_kernel<<<(N_NODES_C + 3) / 4, 256, 0, stream>>>(feat_hd, attn_l, attn_r, el, er);

  z_kernel<<<(N_EDGES_C * HEADS_C + 255) / 256, 256, 0, stream>>>(el, er, src, dst, z);

  agg_kernel<<<(N_EDGES_C + 3) / 4, 256, 0, stream>>>(feat_hd, el, er, src, dst, z, out);
}

// Round 2
// 388.349 us; speedup vs baseline: 7.3996x; 7.3996x over previous
//
#include <hip/hip_runtime.h>

#define N_NODES_C 50000
#define N_EDGES_C 800000
#define IN_FEATS_C 128
#define HEADS_C 8
#define HD_C 256            // HEADS * OUT_FEATS
#define NEG_SLOPE_C 0.2f
#define SCAN_BS 1024
#define SCAN_NBLK ((N_NODES_C + SCAN_BS - 1) / SCAN_BS)   // 49

// ---------------- GEMM: feat_hd[n][c] = sum_k feat[n][k] * W[c][k] ----------------
#define TILE_N 64
#define TILE_C 128
#define KSPLIT 64
#define SW_STRIDE 132
#define SF_STRIDE 68

__global__ __launch_bounds__(256) void gemm_kernel(
    const float* __restrict__ feat, const float* __restrict__ W,
    float* __restrict__ feat_hd) {
  __shared__ float sW[KSPLIT * SW_STRIDE];
  __shared__ float sF[KSPLIT * SF_STRIDE];
  const int bid = blockIdx.x;
  const int ct = bid & 1;
  const int nt = bid >> 1;
  const int n0 = nt * TILE_N;
  const int c0 = ct * TILE_C;
  const int t = threadIdx.x;
  const int tc = t & 15;
  const int tn = t >> 4;

  float acc[4][8];
#pragma unroll
  for (int i = 0; i < 4; ++i)
#pragma unroll
    for (int j = 0; j < 8; ++j) acc[i][j] = 0.f;

  for (int ks = 0; ks < IN_FEATS_C; ks += KSPLIT) {
    __syncthreads();
#pragma unroll
    for (int i = 0; i < (TILE_C * KSPLIT) / 256; ++i) {
      int idx = t + i * 256;
      int c = idx >> 6;
      int k = idx & 63;
      sW[k * SW_STRIDE + c] = W[(c0 + c) * IN_FEATS_C + ks + k];
    }
#pragma unroll
    for (int i = 0; i < (TILE_N * KSPLIT) / 256; ++i) {
      int idx = t + i * 256;
      int n = idx >> 6;
      int k = idx & 63;
      int gn = n0 + n;
      sF[k * SF_STRIDE + n] = (gn < N_NODES_C) ? feat[gn * IN_FEATS_C + ks + k] : 0.f;
    }
    __syncthreads();

    const float* pW = sW + tc * 8;
    const float* pF = sF + tn * 4;
#pragma unroll 4
    for (int k = 0; k < KSPLIT; ++k) {
      float4 w0 = *(const float4*)(pW + k * SW_STRIDE);
      float4 w1 = *(const float4*)(pW + k * SW_STRIDE + 4);
      float4 f0 = *(const float4*)(pF + k * SF_STRIDE);
      float wv[8] = {w0.x, w0.y, w0.z, w0.w, w1.x, w1.y, w1.z, w1.w};
      float fv[4] = {f0.x, f0.y, f0.z, f0.w};
#pragma unroll
      for (int n = 0; n < 4; ++n)
#pragma unroll
        for (int c = 0; c < 8; ++c) acc[n][c] = fmaf(fv[n], wv[c], acc[n][c]);
    }
  }

#pragma unroll
  for (int n = 0; n < 4; ++n) {
    int gn = n0 + tn * 4 + n;
    if (gn >= N_NODES_C) continue;
    float4 o0 = make_float4(acc[n][0], acc[n][1], acc[n][2], acc[n][3]);
    float4 o1 = make_float4(acc[n][4], acc[n][5], acc[n][6], acc[n][7]);
    float* p = feat_hd + (size_t)gn * HD_C + c0 + tc * 8;
    *(float4*)p = o0;
    *(float4*)(p + 4) = o1;
  }
}

// ---------------- el/er ----------------
__global__ __launch_bounds__(256) void elr_kernel(
    const float* __restrict__ feat_hd, const float* __restrict__ attn_l,
    const float* __restrict__ attn_r, float* __restrict__ el,
    float* __restrict__ er) {
  int gid = blockIdx.x * 256 + threadIdx.x;
  int node = gid >> 6;
  int lane = threadIdx.x & 63;
  if (node >= N_NODES_C) return;
  float4 al = *(const float4*)&attn_l[lane * 4];
  float4 ar = *(const float4*)&attn_r[lane * 4];
  float4 f = *(const float4*)&feat_hd[(size_t)node * HD_C + lane * 4];
  float pl = f.x * al.x + f.y * al.y + f.z * al.z + f.w * al.w;
  float pr = f.x * ar.x + f.y * ar.y + f.z * ar.z + f.w * ar.w;
  pl += __shfl_xor(pl, 1); pr += __shfl_xor(pr, 1);
  pl += __shfl_xor(pl, 2); pr += __shfl_xor(pr, 2);
  pl += __shfl_xor(pl, 4); pr += __shfl_xor(pr, 4);
  if ((lane & 7) == 0) {
    el[node * HEADS_C + (lane >> 3)] = pl;
    er[node * HEADS_C + (lane >> 3)] = pr;
  }
}

// ---------------- CSR build ----------------
__global__ __launch_bounds__(256) void deg_kernel(
    const int* __restrict__ dst, int* __restrict__ deg) {
  int e = blockIdx.x * 256 + threadIdx.x;
  if (e < N_EDGES_C) atomicAdd(&deg[dst[e]], 1);
}

// block-wise inclusive scan (Hillis-Steele, 1024/block); writes inclusive into
// row_start and block total into bsum
__global__ __launch_bounds__(SCAN_BS) void scan1_kernel(
    const int* __restrict__ deg, int* __restrict__ row_start,
    int* __restrict__ bsum) {
  __shared__ int s[SCAN_BS];
  int b = blockIdx.x, t = threadIdx.x;
  int i = b * SCAN_BS + t;
  int v = (i < N_NODES_C) ? deg[i] : 0;
  s[t] = v;
  __syncthreads();
#pragma unroll
  for (int off = 1; off < SCAN_BS; off <<= 1) {
    int add = (t >= off) ? s[t - off] : 0;
    __syncthreads();
    s[t] += add;
    __syncthreads();
  }
  if (i < N_NODES_C) row_start[i] = s[t];
  if (t == SCAN_BS - 1) bsum[b] = s[t];
}

// one wave scans the (49) block sums -> exclusive block offsets
__global__ __launch_bounds__(64) void scan2_kernel(
    const int* __restrict__ bsum, int* __restrict__ boff) {
  int t = threadIdx.x;
  int own = (t < SCAN_NBLK) ? bsum[t] : 0;
  int v = own;
#pragma unroll
  for (int off = 1; off < 64; off <<= 1) {
    int u = __shfl_up(v, off);
    if (t >= off) v += u;
  }
  if (t < SCAN_NBLK) boff[t] = v - own;
}

// row_start: inclusive -> exclusive, plus block offset (in-place safe)
__global__ __launch_bounds__(256) void scan3_kernel(
    const int* __restrict__ deg, const int* __restrict__ boff,
    int* __restrict__ row_start) {
  int i = blockIdx.x * 256 + threadIdx.x;
  if (i < N_NODES_C) row_start[i] = row_start[i] - deg[i] + boff[i >> 10];
}

__global__ __launch_bounds__(256) void scatter_kernel(
    const int* __restrict__ src, const int* __restrict__ dst,
    const int* __restrict__ row_start, int* __restrict__ cursor,
    int* __restrict__ csr_src) {
  int e = blockIdx.x * 256 + threadIdx.x;
  if (e >= N_EDGES_C) return;
  int d = dst[e];
  int pos = atomicAdd(&cursor[d], 1);
  csr_src[row_start[d] + pos] = src[e];
}

// ---------------- aggregation over CSR: wave per dst node ----------------
// lane owns 4 contiguous channels (c = lane*4, head = lane>>3).
// Accumulates Sum(exp*feat) and Sum(exp) together -> no separate z pass,
// no atomics, single float4 store per lane.
__global__ __launch_bounds__(256) void agg_csr_kernel(
    const float* __restrict__ feat_hd, const float* __restrict__ el,
    const float* __restrict__ er, const int* __restrict__ row_start,
    const int* __restrict__ deg, const int* __restrict__ csr_src,
    float* __restrict__ out) {
  int gid = blockIdx.x * 256 + threadIdx.x;
  int node = gid >> 6;
  int lane = threadIdx.x & 63;
  if (node >= N_NODES_C) return;
  int h = lane >> 3;
  int c = lane * 4;
  float er_d = er[node * HEADS_C + h];
  int rs = row_start[node];
  int dg = deg[node];
  float4 acc = make_float4(0.f, 0.f, 0.f, 0.f);
  float zsum = 0.f;
  for (int i = 0; i < dg; ++i) {
    int s = csr_src[rs + i];
    float x = el[s * HEADS_C + h] + er_d;
    x = x > 0.f ? x : NEG_SLOPE_C * x;
    float w = __expf(x);
    zsum += w;
    float4 f = *(const float4*)&feat_hd[(size_t)s * HD_C + c];
    acc.x = fmaf(w, f.x, acc.x);
    acc.y = fmaf(w, f.y, acc.y);
    acc.z = fmaf(w, f.z, acc.z);
    acc.w = fmaf(w, f.w, acc.w);
  }
  float inv = (dg > 0) ? 1.f / zsum : 0.f;
  acc.x *= inv; acc.y *= inv; acc.z *= inv; acc.w *= inv;
  *(float4*)&out[(size_t)node * HD_C + c] = acc;
}

extern "C" void kernel_launch(void* const* d_in, const int* in_sizes, int n_in,
                              void* d_out, int out_size, void* d_ws, size_t ws_size,
                              hipStream_t stream) {
  const float* feat   = (const float*)d_in[0];
  const float* W      = (const float*)d_in[1];
  const float* attn_l = (const float*)d_in[2];
  const float* attn_r = (const float*)d_in[3];
  const int* src      = (const int*)d_in[4];
  const int* dst      = (const int*)d_in[5];
  float* out = (float*)d_out;

  char* ws = (char*)d_ws;
  float* feat_hd = (float*)ws;                      ws += (size_t)N_NODES_C * HD_C * 4;      // 51.2 MB
  float* el      = (float*)ws;                      ws += (size_t)N_NODES_C * HEADS_C * 4;   // 1.6 MB
  float* er      = (float*)ws;                      ws += (size_t)N_NODES_C * HEADS_C * 4;   // 1.6 MB
  int* deg       = (int*)ws;                        ws += (size_t)N_NODES_C * 4;
  int* row_start = (int*)ws;                        ws += (size_t)N_NODES_C * 4;
  int* cursor    = (int*)ws;                        ws += (size_t)N_NODES_C * 4;
  int* bsum      = (int*)ws;                        ws += 64 * 4;
  int* boff      = (int*)ws;                        ws += 64 * 4;
  int* csr_src   = (int*)ws;                        ws += (size_t)N_EDGES_C * 4;             // 3.2 MB

  hipMemsetAsync(deg, 0, (size_t)N_NODES_C * 4, stream);
  hipMemsetAsync(cursor, 0, (size_t)N_NODES_C * 4, stream);

  int node_tiles = (N_NODES_C + TILE_N - 1) / TILE_N;
  gemm_kernel<<<node_tiles * 2, 256, 0, stream>>>(feat, W, feat_hd);

  elr_kernel<<<(N_NODES_C + 3) / 4, 256, 0, stream>>>(feat_hd, attn_l, attn_r, el, er);

  deg_kernel<<<(N_EDGES_C + 255) / 256, 256, 0, stream>>>(dst, deg);
  scan1_kernel<<<SCAN_NBLK, SCAN_BS, 0, stream>>>(deg, row_start, bsum);
  scan2_kernel<<<1, 64, 0, stream>>>(bsum, boff);
  scan3_kernel<<<(N_NODES_C + 255) / 256, 256, 0, stream>>>(deg, boff, row_start);
  scatter_kernel<<<(N_EDGES_C + 255) / 256, 256, 0, stream>>>(src, dst, row_start, cursor, csr_src);

  agg_csr_kernel<<<(N_NODES_C + 3) / 4, 256, 0, stream>>>(
      feat_hd, el, er, row_start, deg, csr_src, out);
}

// Round 3
// 315.801 us; speedup vs baseline: 9.0995x; 1.2297x over previous
//
#include <hip/hip_runtime.h>

#define N_NODES_C 50000
#define N_EDGES_C 800000
#define IN_FEATS_C 128
#define HEADS_C 8
#define HD_C 256            // HEADS * OUT_FEATS
#define NEG_SLOPE_C 0.2f
#define SCAN_BS 1024
#define SCAN_NBLK ((N_NODES_C + SCAN_BS - 1) / SCAN_BS)   // 49

__device__ inline unsigned short f2bf(float f) {
  unsigned int u = __float_as_uint(f);
  unsigned int r = (u + 0x7FFFu + ((u >> 16) & 1u)) >> 16;   // RNE
  return (unsigned short)r;
}
__device__ inline float bf2f(unsigned short s) {
  unsigned int u = ((unsigned int)s) << 16;
  return __uint_as_float(u);
}

// ---------------- GEMM + fused el/er + bf16 output ----------------
// feat_hd[n][c] = sum_k feat[n][k] * W[c][k], written as bf16 only.
// Each block: 64 nodes x 128 channels (= 4 complete heads) -> computes
// el/er for those (node, head) pairs exactly from fp32 accumulators.
#define TILE_N 64
#define TILE_C 128
#define KSPLIT 64
#define SW_STRIDE 132
#define SF_STRIDE 68

__global__ __launch_bounds__(256) void gemm_kernel(
    const float* __restrict__ feat, const float* __restrict__ W,
    const float* __restrict__ attn_l, const float* __restrict__ attn_r,
    unsigned short* __restrict__ feat_hd_bf,
    float* __restrict__ el, float* __restrict__ er) {
  __shared__ float sW[KSPLIT * SW_STRIDE];
  __shared__ float sF[KSPLIT * SF_STRIDE];
  const int bid = blockIdx.x;
  const int ct = bid & 1;        // channel tile (4 heads each)
  const int nt = bid >> 1;
  const int n0 = nt * TILE_N;
  const int c0 = ct * TILE_C;
  const int t = threadIdx.x;
  const int tc = t & 15;         // channel group: 8 ch at c0 + tc*8
  const int tn = t >> 4;         // node group: 4 nodes at n0 + tn*4

  float acc[4][8];
#pragma unroll
  for (int i = 0; i < 4; ++i)
#pragma unroll
    for (int j = 0; j < 8; ++j) acc[i][j] = 0.f;

  for (int ks = 0; ks < IN_FEATS_C; ks += KSPLIT) {
    __syncthreads();
#pragma unroll
    for (int i = 0; i < (TILE_C * KSPLIT) / 256; ++i) {
      int idx = t + i * 256;
      int c = idx >> 6;
      int k = idx & 63;
      sW[k * SW_STRIDE + c] = W[(c0 + c) * IN_FEATS_C + ks + k];
    }
#pragma unroll
    for (int i = 0; i < (TILE_N * KSPLIT) / 256; ++i) {
      int idx = t + i * 256;
      int n = idx >> 6;
      int k = idx & 63;
      int gn = n0 + n;
      sF[k * SF_STRIDE + n] = (gn < N_NODES_C) ? feat[gn * IN_FEATS_C + ks + k] : 0.f;
    }
    __syncthreads();

    const float* pW = sW + tc * 8;
    const float* pF = sF + tn * 4;
#pragma unroll 4
    for (int k = 0; k < KSPLIT; ++k) {
      float4 w0 = *(const float4*)(pW + k * SW_STRIDE);
      float4 w1 = *(const float4*)(pW + k * SW_STRIDE + 4);
      float4 f0 = *(const float4*)(pF + k * SF_STRIDE);
      float wv[8] = {w0.x, w0.y, w0.z, w0.w, w1.x, w1.y, w1.z, w1.w};
      float fv[4] = {f0.x, f0.y, f0.z, f0.w};
#pragma unroll
      for (int n = 0; n < 4; ++n)
#pragma unroll
        for (int c = 0; c < 8; ++c) acc[n][c] = fmaf(fv[n], wv[c], acc[n][c]);
    }
  }

  // attention vectors for this thread's 8 channels
  float4 al0 = *(const float4*)&attn_l[c0 + tc * 8];
  float4 al1 = *(const float4*)&attn_l[c0 + tc * 8 + 4];
  float4 ar0 = *(const float4*)&attn_r[c0 + tc * 8];
  float4 ar1 = *(const float4*)&attn_r[c0 + tc * 8 + 4];
  const int head = ct * 4 + (tc >> 2);

#pragma unroll
  for (int n = 0; n < 4; ++n) {
    int gn = n0 + tn * 4 + n;
    bool valid = (gn < N_NODES_C);
    // bf16 store (8 ch = 16 B)
    if (valid) {
      uint4 pk;
      pk.x = (unsigned int)f2bf(acc[n][0]) | ((unsigned int)f2bf(acc[n][1]) << 16);
      pk.y = (unsigned int)f2bf(acc[n][2]) | ((unsigned int)f2bf(acc[n][3]) << 16);
      pk.z = (unsigned int)f2bf(acc[n][4]) | ((unsigned int)f2bf(acc[n][5]) << 16);
      pk.w = (unsigned int)f2bf(acc[n][6]) | ((unsigned int)f2bf(acc[n][7]) << 16);
      *(uint4*)&feat_hd_bf[(size_t)gn * HD_C + c0 + tc * 8] = pk;
    }
    // el/er partial over this thread's 8 channels
    float pl = acc[n][0] * al0.x + acc[n][1] * al0.y + acc[n][2] * al0.z + acc[n][3] * al0.w
             + acc[n][4] * al1.x + acc[n][5] * al1.y + acc[n][6] * al1.z + acc[n][7] * al1.w;
    float pr = acc[n][0] * ar0.x + acc[n][1] * ar0.y + acc[n][2] * ar0.z + acc[n][3] * ar0.w
             + acc[n][4] * ar1.x + acc[n][5] * ar1.y + acc[n][6] * ar1.z + acc[n][7] * ar1.w;
    // reduce across the 4 lanes (tc&3) covering this head's 32 channels
    pl += __shfl_xor(pl, 1); pr += __shfl_xor(pr, 1);
    pl += __shfl_xor(pl, 2); pr += __shfl_xor(pr, 2);
    if (valid && (tc & 3) == 0) {
      el[gn * HEADS_C + head] = pl;
      er[gn * HEADS_C + head] = pr;
    }
  }
}

// ---------------- CSR build ----------------
__global__ __launch_bounds__(256) void deg_kernel(
    const int* __restrict__ dst, int* __restrict__ deg) {
  int e = blockIdx.x * 256 + threadIdx.x;
  if (e < N_EDGES_C) atomicAdd(&deg[dst[e]], 1);
}

__global__ __launch_bounds__(SCAN_BS) void scan1_kernel(
    const int* __restrict__ deg, int* __restrict__ row_start,
    int* __restrict__ bsum) {
  __shared__ int s[SCAN_BS];
  int b = blockIdx.x, t = threadIdx.x;
  int i = b * SCAN_BS + t;
  int v = (i < N_NODES_C) ? deg[i] : 0;
  s[t] = v;
  __syncthreads();
#pragma unroll
  for (int off = 1; off < SCAN_BS; off <<= 1) {
    int add = (t >= off) ? s[t - off] : 0;
    __syncthreads();
    s[t] += add;
    __syncthreads();
  }
  if (i < N_NODES_C) row_start[i] = s[t];
  if (t == SCAN_BS - 1) bsum[b] = s[t];
}

__global__ __launch_bounds__(64) void scan2_kernel(
    const int* __restrict__ bsum, int* __restrict__ boff) {
  int t = threadIdx.x;
  int own = (t < SCAN_NBLK) ? bsum[t] : 0;
  int v = own;
#pragma unroll
  for (int off = 1; off < 64; off <<= 1) {
    int u = __shfl_up(v, off);
    if (t >= off) v += u;
  }
  if (t < SCAN_NBLK) boff[t] = v - own;
}

__global__ __launch_bounds__(256) void scan3_kernel(
    const int* __restrict__ deg, const int* __restrict__ boff,
    int* __restrict__ row_start) {
  int i = blockIdx.x * 256 + threadIdx.x;
  if (i < N_NODES_C) row_start[i] = row_start[i] - deg[i] + boff[i >> 10];
}

__global__ __launch_bounds__(256) void scatter_kernel(
    const int* __restrict__ src, const int* __restrict__ dst,
    const int* __restrict__ row_start, int* __restrict__ cursor,
    int* __restrict__ csr_src) {
  int e = blockIdx.x * 256 + threadIdx.x;
  if (e >= N_EDGES_C) return;
  int d = dst[e];
  int pos = atomicAdd(&cursor[d], 1);
  csr_src[row_start[d] + pos] = src[e];
}

// ---------------- aggregation over CSR: wave per dst node ----------------
// lane owns 4 channels (bf16 gather, 8 B/lane/edge), 4-edge software pipeline.
__global__ __launch_bounds__(256) void agg_csr_kernel(
    const unsigned short* __restrict__ feat_hd_bf, const float* __restrict__ el,
    const float* __restrict__ er, const int* __restrict__ row_start,
    const int* __restrict__ deg, const int* __restrict__ csr_src,
    float* __restrict__ out) {
  int gid = blockIdx.x * 256 + threadIdx.x;
  int node = gid >> 6;
  int lane = threadIdx.x & 63;
  if (node >= N_NODES_C) return;
  int h = lane >> 3;
  int c = lane * 4;
  float er_d = er[node * HEADS_C + h];
  int rs = row_start[node];
  int dg = deg[node];
  float4 acc = make_float4(0.f, 0.f, 0.f, 0.f);
  float zsum = 0.f;

  int i = 0;
  for (; i + 4 <= dg; i += 4) {
    int s0 = csr_src[rs + i + 0];
    int s1 = csr_src[rs + i + 1];
    int s2 = csr_src[rs + i + 2];
    int s3 = csr_src[rs + i + 3];
    float e0 = el[s0 * HEADS_C + h];
    float e1 = el[s1 * HEADS_C + h];
    float e2 = el[s2 * HEADS_C + h];
    float e3 = el[s3 * HEADS_C + h];
    ushort4 f0 = *(const ushort4*)&feat_hd_bf[(size_t)s0 * HD_C + c];
    ushort4 f1 = *(const ushort4*)&feat_hd_bf[(size_t)s1 * HD_C + c];
    ushort4 f2 = *(const ushort4*)&feat_hd_bf[(size_t)s2 * HD_C + c];
    ushort4 f3 = *(const ushort4*)&feat_hd_bf[(size_t)s3 * HD_C + c];
    float x0 = e0 + er_d; x0 = x0 > 0.f ? x0 : NEG_SLOPE_C * x0;
    float x1 = e1 + er_d; x1 = x1 > 0.f ? x1 : NEG_SLOPE_C * x1;
    float x2 = e2 + er_d; x2 = x2 > 0.f ? x2 : NEG_SLOPE_C * x2;
    float x3 = e3 + er_d; x3 = x3 > 0.f ? x3 : NEG_SLOPE_C * x3;
    float w0 = __expf(x0), w1 = __expf(x1), w2 = __expf(x2), w3 = __expf(x3);
    zsum += (w0 + w1) + (w2 + w3);
    acc.x = fmaf(w0, bf2f(f0.x), acc.x);
    acc.y = fmaf(w0, bf2f(f0.y), acc.y);
    acc.z = fmaf(w0, bf2f(f0.z), acc.z);
    acc.w = fmaf(w0, bf2f(f0.w), acc.w);
    acc.x = fmaf(w1, bf2f(f1.x), acc.x);
    acc.y = fmaf(w1, bf2f(f1.y), acc.y);
    acc.z = fmaf(w1, bf2f(f1.z), acc.z);
    acc.w = fmaf(w1, bf2f(f1.w), acc.w);
    acc.x = fmaf(w2, bf2f(f2.x), acc.x);
    acc.y = fmaf(w2, bf2f(f2.y), acc.y);
    acc.z = fmaf(w2, bf2f(f2.z), acc.z);
    acc.w = fmaf(w2, bf2f(f2.w), acc.w);
    acc.x = fmaf(w3, bf2f(f3.x), acc.x);
    acc.y = fmaf(w3, bf2f(f3.y), acc.y);
    acc.z = fmaf(w3, bf2f(f3.z), acc.z);
    acc.w = fmaf(w3, bf2f(f3.w), acc.w);
  }
  for (; i < dg; ++i) {
    int s = csr_src[rs + i];
    float x = el[s * HEADS_C + h] + er_d;
    x = x > 0.f ? x : NEG_SLOPE_C * x;
    float w = __expf(x);
    zsum += w;
    ushort4 f = *(const ushort4*)&feat_hd_bf[(size_t)s * HD_C + c];
    acc.x = fmaf(w, bf2f(f.x), acc.x);
    acc.y = fmaf(w, bf2f(f.y), acc.y);
    acc.z = fmaf(w, bf2f(f.z), acc.z);
    acc.w = fmaf(w, bf2f(f.w), acc.w);
  }

  float inv = (dg > 0) ? 1.f / zsum : 0.f;
  acc.x *= inv; acc.y *= inv; acc.z *= inv; acc.w *= inv;
  *(float4*)&out[(size_t)node * HD_C + c] = acc;
}

extern "C" void kernel_launch(void* const* d_in, const int* in_sizes, int n_in,
                              void* d_out, int out_size, void* d_ws, size_t ws_size,
                              hipStream_t stream) {
  const float* feat   = (const float*)d_in[0];
  const float* W      = (const float*)d_in[1];
  const float* attn_l = (const float*)d_in[2];
  const float* attn_r = (const float*)d_in[3];
  const int* src      = (const int*)d_in[4];
  const int* dst      = (const int*)d_in[5];
  float* out = (float*)d_out;

  char* ws = (char*)d_ws;
  unsigned short* feat_hd_bf = (unsigned short*)ws;  ws += (size_t)N_NODES_C * HD_C * 2;     // 25.6 MB
  float* el      = (float*)ws;                       ws += (size_t)N_NODES_C * HEADS_C * 4;  // 1.6 MB
  float* er      = (float*)ws;                       ws += (size_t)N_NODES_C * HEADS_C * 4;  // 1.6 MB
  int* deg       = (int*)ws;                         ws += (size_t)N_NODES_C * 4;
  int* row_start = (int*)ws;                         ws += (size_t)N_NODES_C * 4;
  int* cursor    = (int*)ws;                         ws += (size_t)N_NODES_C * 4;
  int* bsum      = (int*)ws;                         ws += 64 * 4;
  int* boff      = (int*)ws;                         ws += 64 * 4;
  int* csr_src   = (int*)ws;                         ws += (size_t)N_EDGES_C * 4;            // 3.2 MB

  hipMemsetAsync(deg, 0, (size_t)N_NODES_C * 4, stream);
  hipMemsetAsync(cursor, 0, (size_t)N_NODES_C * 4, stream);

  int node_tiles = (N_NODES_C + TILE_N - 1) / TILE_N;
  gemm_kernel<<<node_tiles * 2, 256, 0, stream>>>(feat, W, attn_l, attn_r,
                                                  feat_hd_bf, el, er);

  deg_kernel<<<(N_EDGES_C + 255) / 256, 256, 0, stream>>>(dst, deg);
  scan1_kernel<<<SCAN_NBLK, SCAN_BS, 0, stream>>>(deg, row_start, bsum);
  scan2_kernel<<<1, 64, 0, stream>>>(bsum, boff);
  scan3_kernel<<<(N_NODES_C + 255) / 256, 256, 0, stream>>>(deg, boff, row_start);
  scatter_kernel<<<(N_EDGES_C + 255) / 256, 256, 0, stream>>>(src, dst, row_start, cursor, csr_src);

  agg_csr_kernel<<<(N_NODES_C + 3) / 4, 256, 0, stream>>>(
      feat_hd_bf, el, er, row_start, deg, csr_src, out);
}

// Round 4
// 285.290 us; speedup vs baseline: 10.0727x; 1.1069x over previous
//
#include <hip/hip_runtime.h>

#define N_NODES_C 50000
#define N_EDGES_C 800000
#define IN_FEATS_C 128
#define HEADS_C 8
#define HD_C 256            // HEADS * OUT_FEATS
#define NEG_SLOPE_C 0.2f
#define SCAN_BS 1024
#define SCAN_NBLK ((N_NODES_C + SCAN_BS - 1) / SCAN_BS)   // 49

typedef __attribute__((ext_vector_type(8))) short bf16x8;
typedef __attribute__((ext_vector_type(4))) float floatx4;

__device__ inline unsigned short f2bf(float f) {
  unsigned int u = __float_as_uint(f);
  unsigned int r = (u + 0x7FFFu + ((u >> 16) & 1u)) >> 16;   // RNE
  return (unsigned short)r;
}
__device__ inline float bf2f(unsigned short s) {
  unsigned int u = ((unsigned int)s) << 16;
  return __uint_as_float(u);
}

// ---------------- proj: al_proj[h][k] = sum_d W[h*32+d][k] * attn_l[h][d] ----
// Exact fp32 factoring of el/er out of the (bf16) GEMM.
__global__ __launch_bounds__(256) void proj_kernel(
    const float* __restrict__ W, const float* __restrict__ attn_l,
    const float* __restrict__ attn_r, float* __restrict__ alp,
    float* __restrict__ arp) {
  int idx = blockIdx.x * 256 + threadIdx.x;   // 0..1023 = (h,k)
  int h = idx >> 7;
  int k = idx & 127;
  float sl = 0.f, sr = 0.f;
#pragma unroll 8
  for (int d = 0; d < 32; ++d) {
    float w = W[(size_t)(h * 32 + d) * IN_FEATS_C + k];
    sl = fmaf(w, attn_l[h * 32 + d], sl);
    sr = fmaf(w, attn_r[h * 32 + d], sr);
  }
  alp[idx] = sl;
  arp[idx] = sr;
}

// ---------------- el/er: exact fp32, wave per node ----------------
// lane: head = lane>>3, k-range = (lane&7)*16..+15; reduce over 8 lanes.
__global__ __launch_bounds__(256) void elr_kernel(
    const float* __restrict__ feat, const float* __restrict__ alp,
    const float* __restrict__ arp, float* __restrict__ el,
    float* __restrict__ er) {
  __shared__ float sAl[8 * 132];
  __shared__ float sAr[8 * 132];
  int t = threadIdx.x;
#pragma unroll
  for (int i = 0; i < 4; ++i) {
    int idx = t + i * 256;
    int h = idx >> 7, k = idx & 127;
    sAl[h * 132 + k] = alp[idx];
    sAr[h * 132 + k] = arp[idx];
  }
  __syncthreads();
  int wid = t >> 6, lane = t & 63;
  int node = blockIdx.x * 4 + wid;
  if (node >= N_NODES_C) return;
  int h = lane >> 3;
  int kb = (lane & 7) * 16;
  const float* fr = &feat[(size_t)node * IN_FEATS_C + kb];
  float4 f0 = *(const float4*)(fr + 0);
  float4 f1 = *(const float4*)(fr + 4);
  float4 f2 = *(const float4*)(fr + 8);
  float4 f3 = *(const float4*)(fr + 12);
  const float* al = &sAl[h * 132 + kb];
  const float* ar = &sAr[h * 132 + kb];
  float4 a0 = *(const float4*)(al + 0), a1 = *(const float4*)(al + 4);
  float4 a2 = *(const float4*)(al + 8), a3 = *(const float4*)(al + 12);
  float4 b0 = *(const float4*)(ar + 0), b1 = *(const float4*)(ar + 4);
  float4 b2 = *(const float4*)(ar + 8), b3 = *(const float4*)(ar + 12);
  float pl = f0.x * a0.x + f0.y * a0.y + f0.z * a0.z + f0.w * a0.w
           + f1.x * a1.x + f1.y * a1.y + f1.z * a1.z + f1.w * a1.w
           + f2.x * a2.x + f2.y * a2.y + f2.z * a2.z + f2.w * a2.w
           + f3.x * a3.x + f3.y * a3.y + f3.z * a3.z + f3.w * a3.w;
  float pr = f0.x * b0.x + f0.y * b0.y + f0.z * b0.z + f0.w * b0.w
           + f1.x * b1.x + f1.y * b1.y + f1.z * b1.z + f1.w * b1.w
           + f2.x * b2.x + f2.y * b2.y + f2.z * b2.z + f2.w * b2.w
           + f3.x * b3.x + f3.y * b3.y + f3.z * b3.z + f3.w * b3.w;
  pl += __shfl_xor(pl, 1); pr += __shfl_xor(pr, 1);
  pl += __shfl_xor(pl, 2); pr += __shfl_xor(pr, 2);
  pl += __shfl_xor(pl, 4); pr += __shfl_xor(pr, 4);
  if ((lane & 7) == 0) {
    el[node * HEADS_C + h] = pl;
    er[node * HEADS_C + h] = pr;
  }
}

// ---------------- MFMA bf16 GEMM: feat_hd_bf = bf16(feat @ W.T) ----------------
// Block: 128 nodes x 128 channels, K=128 in one shot. 4 waves, each 64x64.
// LDS stride 136 shorts (272 B = 17*16: rows 16B-aligned, banks spread).
#define LDT 136
__global__ __launch_bounds__(256) void mfma_gemm_kernel(
    const float* __restrict__ feat, const float* __restrict__ W,
    unsigned short* __restrict__ feat_hd_bf) {
  __shared__ unsigned short sAB[2 * 128 * LDT];
  unsigned short* sA = sAB;
  unsigned short* sB = sAB + 128 * LDT;
  unsigned short* sOut = sAB;          // reused after compute

  const int bid = blockIdx.x;
  const int nt = bid & 1;              // channel tile
  const int mt = bid >> 1;             // node tile
  const int m0 = mt * 128;
  const int n0 = nt * 128;
  const int t = threadIdx.x;

  // stage A: 128 rows x 32 float4 of feat -> bf16
#pragma unroll
  for (int i = 0; i < 16; ++i) {
    int idx = t + i * 256;
    int row = idx >> 5;
    int c4 = idx & 31;
    int gn = m0 + row;
    float4 v = (gn < N_NODES_C)
                   ? *(const float4*)&feat[(size_t)gn * IN_FEATS_C + c4 * 4]
                   : make_float4(0.f, 0.f, 0.f, 0.f);
    ushort4 b;
    b.x = f2bf(v.x); b.y = f2bf(v.y); b.z = f2bf(v.z); b.w = f2bf(v.w);
    *(ushort4*)&sA[row * LDT + c4 * 4] = b;
  }
  // stage B: 128 channel rows x 32 float4 of W -> bf16
#pragma unroll
  for (int i = 0; i < 16; ++i) {
    int idx = t + i * 256;
    int row = idx >> 5;
    int c4 = idx & 31;
    float4 v = *(const float4*)&W[(size_t)(n0 + row) * IN_FEATS_C + c4 * 4];
    ushort4 b;
    b.x = f2bf(v.x); b.y = f2bf(v.y); b.z = f2bf(v.z); b.w = f2bf(v.w);
    *(ushort4*)&sB[row * LDT + c4 * 4] = b;
  }
  __syncthreads();

  const int wid = t >> 6;
  const int lane = t & 63;
  const int quad = lane >> 4;
  const int l16 = lane & 15;
  const int wm = (wid & 1) * 64;
  const int wn = (wid >> 1) * 64;

  floatx4 acc[4][4];
#pragma unroll
  for (int i = 0; i < 4; ++i)
#pragma unroll
    for (int j = 0; j < 4; ++j) acc[i][j] = (floatx4){0.f, 0.f, 0.f, 0.f};

#pragma unroll
  for (int ks = 0; ks < 4; ++ks) {
    int k0 = ks * 32 + quad * 8;
    bf16x8 af[4], bfv[4];
#pragma unroll
    for (int m2 = 0; m2 < 4; ++m2)
      af[m2] = *(const bf16x8*)&sA[(wm + m2 * 16 + l16) * LDT + k0];
#pragma unroll
    for (int n2 = 0; n2 < 4; ++n2)
      bfv[n2] = *(const bf16x8*)&sB[(wn + n2 * 16 + l16) * LDT + k0];
#pragma unroll
    for (int m2 = 0; m2 < 4; ++m2)
#pragma unroll
      for (int n2 = 0; n2 < 4; ++n2)
        acc[m2][n2] = __builtin_amdgcn_mfma_f32_16x16x32_bf16(
            af[m2], bfv[n2], acc[m2][n2], 0, 0, 0);
  }

  __syncthreads();   // everyone done reading sA/sB

  // epilogue: D layout col=l16, row=quad*4+reg -> repack via LDS
#pragma unroll
  for (int m2 = 0; m2 < 4; ++m2)
#pragma unroll
    for (int n2 = 0; n2 < 4; ++n2)
#pragma unroll
      for (int r = 0; r < 4; ++r) {
        int row = wm + m2 * 16 + quad * 4 + r;
        int col = wn + n2 * 16 + l16;
        sOut[row * LDT + col] = f2bf(acc[m2][n2][r]);
      }
  __syncthreads();

  // coalesced store: 128 rows x 16 chunks of 8 shorts (16 B)
#pragma unroll
  for (int i = 0; i < 8; ++i) {
    int idx = t + i * 256;
    int row = idx >> 4;
    int ch = idx & 15;
    int gn = m0 + row;
    if (gn < N_NODES_C) {
      *(uint4*)&feat_hd_bf[(size_t)gn * HD_C + n0 + ch * 8] =
          *(const uint4*)&sOut[row * LDT + ch * 8];
    }
  }
}

// ---------------- CSR build ----------------
__global__ __launch_bounds__(256) void deg_kernel(
    const int* __restrict__ dst, int* __restrict__ deg) {
  int e = blockIdx.x * 256 + threadIdx.x;
  if (e < N_EDGES_C) atomicAdd(&deg[dst[e]], 1);
}

__global__ __launch_bounds__(SCAN_BS) void scan1_kernel(
    const int* __restrict__ deg, int* __restrict__ row_start,
    int* __restrict__ bsum) {
  __shared__ int s[SCAN_BS];
  int b = blockIdx.x, t = threadIdx.x;
  int i = b * SCAN_BS + t;
  int v = (i < N_NODES_C) ? deg[i] : 0;
  s[t] = v;
  __syncthreads();
#pragma unroll
  for (int off = 1; off < SCAN_BS; off <<= 1) {
    int add = (t >= off) ? s[t - off] : 0;
    __syncthreads();
    s[t] += add;
    __syncthreads();
  }
  if (i < N_NODES_C) row_start[i] = s[t];
  if (t == SCAN_BS - 1) bsum[b] = s[t];
}

__global__ __launch_bounds__(64) void scan2_kernel(
    const int* __restrict__ bsum, int* __restrict__ boff) {
  int t = threadIdx.x;
  int own = (t < SCAN_NBLK) ? bsum[t] : 0;
  int v = own;
#pragma unroll
  for (int off = 1; off < 64; off <<= 1) {
    int u = __shfl_up(v, off);
    if (t >= off) v += u;
  }
  if (t < SCAN_NBLK) boff[t] = v - own;
}

__global__ __launch_bounds__(256) void scan3_kernel(
    const int* __restrict__ deg, const int* __restrict__ boff,
    int* __restrict__ row_start) {
  int i = blockIdx.x * 256 + threadIdx.x;
  if (i < N_NODES_C) row_start[i] = row_start[i] - deg[i] + boff[i >> 10];
}

__global__ __launch_bounds__(256) void scatter_kernel(
    const int* __restrict__ src, const int* __restrict__ dst,
    const int* __restrict__ row_start, int* __restrict__ cursor,
    int* __restrict__ csr_src) {
  int e = blockIdx.x * 256 + threadIdx.x;
  if (e >= N_EDGES_C) return;
  int d = dst[e];
  int pos = atomicAdd(&cursor[d], 1);
  csr_src[row_start[d] + pos] = src[e];
}

// ---------------- aggregation over CSR: wave per dst node ----------------
__global__ __launch_bounds__(256) void agg_csr_kernel(
    const unsigned short* __restrict__ feat_hd_bf, const float* __restrict__ el,
    const float* __restrict__ er, const int* __restrict__ row_start,
    const int* __restrict__ deg, const int* __restrict__ csr_src,
    float* __restrict__ out) {
  int gid = blockIdx.x * 256 + threadIdx.x;
  int node = gid >> 6;
  int lane = threadIdx.x & 63;
  if (node >= N_NODES_C) return;
  int h = lane >> 3;
  int c = lane * 4;
  float er_d = er[node * HEADS_C + h];
  int rs = row_start[node];
  int dg = deg[node];
  float4 acc = make_float4(0.f, 0.f, 0.f, 0.f);
  float zsum = 0.f;

  int i = 0;
  for (; i + 4 <= dg; i += 4) {
    int s0 = csr_src[rs + i + 0];
    int s1 = csr_src[rs + i + 1];
    int s2 = csr_src[rs + i + 2];
    int s3 = csr_src[rs + i + 3];
    float e0 = el[s0 * HEADS_C + h];
    float e1 = el[s1 * HEADS_C + h];
    float e2 = el[s2 * HEADS_C + h];
    float e3 = el[s3 * HEADS_C + h];
    ushort4 f0 = *(const ushort4*)&feat_hd_bf[(size_t)s0 * HD_C + c];
    ushort4 f1 = *(const ushort4*)&feat_hd_bf[(size_t)s1 * HD_C + c];
    ushort4 f2 = *(const ushort4*)&feat_hd_bf[(size_t)s2 * HD_C + c];
    ushort4 f3 = *(const ushort4*)&feat_hd_bf[(size_t)s3 * HD_C + c];
    float x0 = e0 + er_d; x0 = x0 > 0.f ? x0 : NEG_SLOPE_C * x0;
    float x1 = e1 + er_d; x1 = x1 > 0.f ? x1 : NEG_SLOPE_C * x1;
    float x2 = e2 + er_d; x2 = x2 > 0.f ? x2 : NEG_SLOPE_C * x2;
    float x3 = e3 + er_d; x3 = x3 > 0.f ? x3 : NEG_SLOPE_C * x3;
    float w0 = __expf(x0), w1 = __expf(x1), w2 = __expf(x2), w3 = __expf(x3);
    zsum += (w0 + w1) + (w2 + w3);
    acc.x = fmaf(w0, bf2f(f0.x), acc.x);
    acc.y = fmaf(w0, bf2f(f0.y), acc.y);
    acc.z = fmaf(w0, bf2f(f0.z), acc.z);
    acc.w = fmaf(w0, bf2f(f0.w), acc.w);
    acc.x = fmaf(w1, bf2f(f1.x), acc.x);
    acc.y = fmaf(w1, bf2f(f1.y), acc.y);
    acc.z = fmaf(w1, bf2f(f1.z), acc.z);
    acc.w = fmaf(w1, bf2f(f1.w), acc.w);
    acc.x = fmaf(w2, bf2f(f2.x), acc.x);
    acc.y = fmaf(w2, bf2f(f2.y), acc.y);
    acc.z = fmaf(w2, bf2f(f2.z), acc.z);
    acc.w = fmaf(w2, bf2f(f2.w), acc.w);
    acc.x = fmaf(w3, bf2f(f3.x), acc.x);
    acc.y = fmaf(w3, bf2f(f3.y), acc.y);
    acc.z = fmaf(w3, bf2f(f3.z), acc.z);
    acc.w = fmaf(w3, bf2f(f3.w), acc.w);
  }
  for (; i < dg; ++i) {
    int s = csr_src[rs + i];
    float x = el[s * HEADS_C + h] + er_d;
    x = x > 0.f ? x : NEG_SLOPE_C * x;
    float w = __expf(x);
    zsum += w;
    ushort4 f = *(const ushort4*)&feat_hd_bf[(size_t)s * HD_C + c];
    acc.x = fmaf(w, bf2f(f.x), acc.x);
    acc.y = fmaf(w, bf2f(f.y), acc.y);
    acc.z = fmaf(w, bf2f(f.z), acc.z);
    acc.w = fmaf(w, bf2f(f.w), acc.w);
  }

  float inv = (dg > 0) ? 1.f / zsum : 0.f;
  acc.x *= inv; acc.y *= inv; acc.z *= inv; acc.w *= inv;
  *(float4*)&out[(size_t)node * HD_C + c] = acc;
}

extern "C" void kernel_launch(void* const* d_in, const int* in_sizes, int n_in,
                              void* d_out, int out_size, void* d_ws, size_t ws_size,
                              hipStream_t stream) {
  const float* feat   = (const float*)d_in[0];
  const float* W      = (const float*)d_in[1];
  const float* attn_l = (const float*)d_in[2];
  const float* attn_r = (const float*)d_in[3];
  const int* src      = (const int*)d_in[4];
  const int* dst      = (const int*)d_in[5];
  float* out = (float*)d_out;

  char* ws = (char*)d_ws;
  unsigned short* feat_hd_bf = (unsigned short*)ws;  ws += (size_t)N_NODES_C * HD_C * 2;     // 25.6 MB
  float* el      = (float*)ws;                       ws += (size_t)N_NODES_C * HEADS_C * 4;  // 1.6 MB
  float* er      = (float*)ws;                       ws += (size_t)N_NODES_C * HEADS_C * 4;  // 1.6 MB
  float* alp     = (float*)ws;                       ws += (size_t)HEADS_C * IN_FEATS_C * 4;
  float* arp     = (float*)ws;                       ws += (size_t)HEADS_C * IN_FEATS_C * 4;
  int* deg       = (int*)ws;                         ws += (size_t)N_NODES_C * 4;
  int* row_start = (int*)ws;                         ws += (size_t)N_NODES_C * 4;
  int* cursor    = (int*)ws;                         ws += (size_t)N_NODES_C * 4;
  int* bsum      = (int*)ws;                         ws += 64 * 4;
  int* boff      = (int*)ws;                         ws += 64 * 4;
  int* csr_src   = (int*)ws;                         ws += (size_t)N_EDGES_C * 4;            // 3.2 MB

  hipMemsetAsync(deg, 0, (size_t)N_NODES_C * 4, stream);
  hipMemsetAsync(cursor, 0, (size_t)N_NODES_C * 4, stream);

  // independent front-ends
  int m_tiles = (N_NODES_C + 127) / 128;   // 391
  mfma_gemm_kernel<<<m_tiles * 2, 256, 0, stream>>>(feat, W, feat_hd_bf);
  proj_kernel<<<4, 256, 0, stream>>>(W, attn_l, attn_r, alp, arp);
  elr_kernel<<<(N_NODES_C + 3) / 4, 256, 0, stream>>>(feat, alp, arp, el, er);

  deg_kernel<<<(N_EDGES_C + 255) / 256, 256, 0, stream>>>(dst, deg);
  scan1_kernel<<<SCAN_NBLK, SCAN_BS, 0, stream>>>(deg, row_start, bsum);
  scan2_kernel<<<1, 64, 0, stream>>>(bsum, boff);
  scan3_kernel<<<(N_NODES_C + 255) / 256, 256, 0, stream>>>(deg, boff, row_start);
  scatter_kernel<<<(N_EDGES_C + 255) / 256, 256, 0, stream>>>(src, dst, row_start, cursor, csr_src);

  agg_csr_kernel<<<(N_NODES_C + 3) / 4, 256, 0, stream>>>(
      feat_hd_bf, el, er, row_start, deg, csr_src, out);
}